// Round 16
// baseline (154.976 us; speedup 1.0000x reference)
//
#include <hip/hip_runtime.h>
#include <hip/hip_bf16.h>
#include <cstdint>

typedef __attribute__((ext_vector_type(8))) short short8;
typedef __attribute__((ext_vector_type(4))) short short4v;
typedef __attribute__((ext_vector_type(4))) float f32x4;
typedef __attribute__((ext_vector_type(16))) float f32x16;
typedef __attribute__((ext_vector_type(4))) unsigned int u32x4;
typedef unsigned short ushort_t;
typedef unsigned int uint32;

#define DEVI static __device__ __forceinline__

DEVI ushort_t f2bf(float f){
  uint32 u = __builtin_bit_cast(uint32, f);
  u += 0x7FFFu + ((u >> 16) & 1u);
  return (ushort_t)(u >> 16);
}
DEVI uint32 cvtpk_bf16(float lo, float hi){
  uint32 r;
  asm("v_cvt_pk_bf16_f32 %0, %1, %2" : "=v"(r) : "v"(lo), "v"(hi));
  return r;
}
DEVI void plswap(uint32& a, uint32& b){
  asm("v_permlane32_swap_b32 %0, %1" : "+v"(a), "+v"(b));
}

typedef __attribute__((address_space(1))) const uint32 g_u32;
typedef __attribute__((address_space(3))) uint32 l_u32;
#define GL_LDS16(gp, lp) __builtin_amdgcn_global_load_lds((g_u32*)(gp), (l_u32*)(lp), 16, 0, 0)

#define MFMA16(a, b, c) __builtin_amdgcn_mfma_f32_16x16x32_bf16(a, b, c, 0, 0, 0)
#define MFMA32(a, b, c) __builtin_amdgcn_mfma_f32_32x32x16_bf16(a, b, c, 0, 0, 0)

// ---------------- fp32 -> bf16 conversion + rope table ----------------
__global__ __launch_bounds__(256) void convert_all(
    const float* __restrict__ x, const float* __restrict__ wq, const float* __restrict__ wk,
    const float* __restrict__ wv, const float* __restrict__ wo,
    ushort_t* __restrict__ xb, ushort_t* __restrict__ wqkv, ushort_t* __restrict__ wob,
    float2* __restrict__ tab){
  int bid = blockIdx.x;
  if (bid >= 6144){
    const int idx = (bid - 6144) * 256 + threadIdx.x;    // 65536
    const int tok = idx >> 5, j = idx & 31;
    const float theta = exp2f(-(float)j * 0.4152410118609203f);   // log2(10000)/32
    const float ang = (float)(tok + 1) * theta;
    float s, c;
    sincosf(ang, &s, &c);
    tab[idx] = make_float2(c, s);
    return;
  }
  const float* src; ushort_t* dst; long base;
  if (bid < 4096){ src = x; dst = xb; base = (long)bid * 2048; }
  else {
    int r = bid - 4096; int sel = r >> 9; int o = r & 511;
    src = sel==0?wq: sel==1?wk: sel==2?wv: wo;
    dst = (sel<3) ? (wqkv + (long)sel * 1048576) : wob;
    base = (long)o * 2048;
  }
  long i = base + (long)threadIdx.x * 8;
  const float* p = src + i;
  float4 a = *(const float4*)p;
  float4 b = *(const float4*)(p + 4);
  short8 v;
  v[0]=(short)f2bf(a.x); v[1]=(short)f2bf(a.y); v[2]=(short)f2bf(a.z); v[3]=(short)f2bf(a.w);
  v[4]=(short)f2bf(b.x); v[5]=(short)f2bf(b.y); v[6]=(short)f2bf(b.z); v[7]=(short)f2bf(b.w);
  *(short8*)(dst + i) = v;
}

// ---------------- QKV GEMM, 128x128 tile, BK=32, tri-buffered, 3 blocks/CU ----------------
// 256 threads, 4 waves (2M x 2N, wave = 64x64). LDS 48 KB. Grid 1536 = 6/CU in
// two fully-occupied rounds. 4 loads/thread/tile staged 2 ahead; ONE vmcnt(4) +
// ONE barrier per tile. Per-XCD 8bm x 24bn region in 8x4 chunks (2MB A + 1MB B in L2).
__global__ __launch_bounds__(256, 3) void gemm_qkv(
    const ushort_t* __restrict__ A, const ushort_t* __restrict__ Bw,
    const float* __restrict__ bq, const float* __restrict__ bk, const float* __restrict__ bv,
    const float2* __restrict__ tab,
    ushort_t* __restrict__ Qb, ushort_t* __restrict__ Kb, ushort_t* __restrict__ Vt){
  __shared__ __align__(16) ushort_t S[24576];   // 48 KB: 3 bufs x (A 8KB | B 8KB)
  const int tid = threadIdx.x;
  const int w = tid >> 6, l = tid & 63, lr = l & 15, lg = l >> 4;
  const int wm = w >> 1, wn = w & 1;            // 2M x 2N, wave = 64x64
  const int xcd = blockIdx.x & 7;
  const int l2  = blockIdx.x >> 3;              // 0..191
  const int bg  = l2 >> 5;                      // 0..5
  const int rem = l2 & 31;
  const int bm  = (xcd << 3) + (rem >> 2);      // 0..63
  const int bn  = (bg << 2) + (rem & 3);        // 0..23
  const int m0 = bm << 7, n0 = bn << 7;
  const int rbase = tid >> 2;                   // 0..63 (+64 for 2nd load)
  const int swzk = (tid & 3) ^ ((tid >> 3) & 3);
  const ushort_t* aS = A  + (long)(m0 + rbase) * 1024 + swzk * 8;
  const ushort_t* bS = Bw + (long)(n0 + rbase) * 1024 + swzk * 8;
  const int slot = (lg ^ ((lr >> 1) & 3)) << 3;
  const int arow = wm * 64 + lr;
  const int brow = wn * 64 + lr;
  f32x4 acc[4][4] = {};

#define STGA(t, bf_) do{ \
    const ushort_t* _s = aS + (long)(t)*32; \
    ushort_t* _d = &S[(bf_)*8192 + tid*8]; \
    GL_LDS16(_s,         _d); \
    GL_LDS16(_s + 65536, _d + 2048); }while(0)
#define STGB(t, bf_) do{ \
    const ushort_t* _s = bS + (long)(t)*32; \
    ushort_t* _d = &S[(bf_)*8192 + 4096 + tid*8]; \
    GL_LDS16(_s,         _d); \
    GL_LDS16(_s + 65536, _d + 2048); }while(0)

  STGA(0,0); STGB(0,0);
  STGA(1,1); STGB(1,1);
  asm volatile("s_waitcnt vmcnt(4)" ::: "memory");
  __builtin_amdgcn_s_barrier();

  int buf = 0;
  for (int t = 0; t < 32; ++t){
    const int nstg = (buf >= 1) ? buf - 1 : 2;     // (t+2)%3
    const ushort_t* SA = &S[buf * 8192];
    const ushort_t* SB = &S[buf * 8192 + 4096];
    short8 af[4], bfv[4];
#pragma unroll
    for (int mi = 0; mi < 4; ++mi) af[mi]  = *(const short8*)&SA[(arow + mi*16)*32 + slot];
#pragma unroll
    for (int nc = 0; nc < 4; ++nc) bfv[nc] = *(const short8*)&SB[(brow + nc*16)*32 + slot];
    if (t < 30){ STGA(t+2, nstg); STGB(t+2, nstg); }
    __builtin_amdgcn_s_setprio(1);
#pragma unroll
    for (int mi = 0; mi < 4; ++mi)
#pragma unroll
      for (int nc = 0; nc < 4; ++nc)
        acc[mi][nc] = MFMA16(af[mi], bfv[nc], acc[mi][nc]);
    __builtin_amdgcn_s_setprio(0);
    if (t < 30)       asm volatile("s_waitcnt vmcnt(4)" ::: "memory");  // tile t+1 resident
    else if (t == 30) asm volatile("s_waitcnt vmcnt(0)" ::: "memory");
    __builtin_amdgcn_s_barrier();
    buf = (buf >= 2) ? 0 : buf + 1;
  }
#undef STGA
#undef STGB

  const int colX = n0 + (wn << 6);
  const int sel = colX >> 10;                // 0=Q 1=K 2=V
  const int h = (colX >> 6) & 15;
  const int cB = (colX & 1023) + lr;
  if (sel < 2){
    ushort_t* dst = sel ? Kb : Qb;
    const float* bp = sel ? bk : bq;
    const float bvs[4] = {bp[cB], bp[cB+16], bp[cB+32], bp[cB+48]};
#pragma unroll
    for (int mi = 0; mi < 4; ++mi){
      const int row0 = m0 + (wm << 6) + mi*16 + lg*4;
#pragma unroll
      for (int i = 0; i < 4; ++i){
        const int r = row0 + i;
        const int b = r >> 11, tok = r & 2047;
#pragma unroll
        for (int nc = 0; nc < 2; ++nc){
          const int j = nc*16 + lr;
          const float2 cs = tab[tok*32 + j];
          const float v0 = acc[mi][nc][i]   + bvs[nc];
          const float v1 = acc[mi][nc+2][i] + bvs[nc+2];
          const long base = (((long)((b<<4) + h) * 2048 + tok) << 6) + j;
          dst[base]      = f2bf(v0 * cs.x - v1 * cs.y);
          dst[base + 32] = f2bf(v1 * cs.x + v0 * cs.y);
        }
      }
    }
  } else {
    // V: LDS transpose -> coalesced Vt writes (wave-private [64 d][72] region)
    const float bvs[4] = {bv[cB], bv[cB+16], bv[cB+32], bv[cB+48]};
    ushort_t* T = &S[w * 4608];          // 4 waves x 4608 = 18432 <= 24576
#pragma unroll
    for (int nc = 0; nc < 4; ++nc){
      const int d = nc*16 + lr;
      const int dx = d & 7;
#pragma unroll
      for (int mi = 0; mi < 4; ++mi){
        const int col = mi*16 + lg*4;
        const int scol = (((col >> 3) ^ dx) << 3) + (col & 7);
        const uint32 p0 = cvtpk_bf16(acc[mi][nc][0] + bvs[nc], acc[mi][nc][1] + bvs[nc]);
        const uint32 p1 = cvtpk_bf16(acc[mi][nc][2] + bvs[nc], acc[mi][nc][3] + bvs[nc]);
        uint32* dp = (uint32*)&T[d*72 + scol];
        dp[0] = p0; dp[1] = p1;
      }
    }
    const int rowbase = m0 + (wm << 6);
    const int b = rowbase >> 11;
    const int tok0 = rowbase & 2047;
    ushort_t* vbase = Vt + (((long)((b << 4) + h)) << 17);   // *64*2048
    const int dl = l >> 3, c8 = l & 7;
#pragma unroll
    for (int it = 0; it < 8; ++it){
      const int d = dl + it*8;
      short8 v = *(const short8*)&T[d*72 + ((c8 ^ (d & 7)) << 3)];
      *(short8*)&vbase[((long)d << 11) + tok0 + (c8 << 3)] = v;
    }
  }
}

// ---------------- output GEMM, 128x128 tile, BK=32, tri-buffered ----------------
__global__ __launch_bounds__(256, 3) void gemm_out(
    const ushort_t* __restrict__ A, const ushort_t* __restrict__ Bw,
    const float* __restrict__ bias, float* __restrict__ Cout){
  __shared__ __align__(16) ushort_t S[24576];   // 48 KB
  const int tid = threadIdx.x;
  const int w = tid >> 6, l = tid & 63, lr = l & 15, lg = l >> 4;
  const int wm = w >> 1, wn = w & 1;
  const int xcd = blockIdx.x & 7;
  const int l6  = blockIdx.x >> 3;              // 0..63
  const int bm  = (xcd << 3) + (l6 >> 3);       // 0..63
  const int bn  = l6 & 7;
  const int m0 = bm << 7, n0 = bn << 7;
  const int rbase = tid >> 2;
  const int swzk = (tid & 3) ^ ((tid >> 3) & 3);
  const ushort_t* aS = A  + (long)(m0 + rbase) * 1024 + swzk * 8;
  const ushort_t* bS = Bw + (long)(n0 + rbase) * 1024 + swzk * 8;
  const int slot = (lg ^ ((lr >> 1) & 3)) << 3;
  const int arow = wm * 64 + lr;
  const int brow = wn * 64 + lr;
  f32x4 acc[4][4] = {};

#define STGA(t, bf_) do{ \
    const ushort_t* _s = aS + (long)(t)*32; \
    ushort_t* _d = &S[(bf_)*8192 + tid*8]; \
    GL_LDS16(_s,         _d); \
    GL_LDS16(_s + 65536, _d + 2048); }while(0)
#define STGB(t, bf_) do{ \
    const ushort_t* _s = bS + (long)(t)*32; \
    ushort_t* _d = &S[(bf_)*8192 + 4096 + tid*8]; \
    GL_LDS16(_s,         _d); \
    GL_LDS16(_s + 65536, _d + 2048); }while(0)

  STGA(0,0); STGB(0,0);
  STGA(1,1); STGB(1,1);
  asm volatile("s_waitcnt vmcnt(4)" ::: "memory");
  __builtin_amdgcn_s_barrier();

  int buf = 0;
  for (int t = 0; t < 32; ++t){
    const int nstg = (buf >= 1) ? buf - 1 : 2;
    const ushort_t* SA = &S[buf * 8192];
    const ushort_t* SB = &S[buf * 8192 + 4096];
    short8 af[4], bfv[4];
#pragma unroll
    for (int mi = 0; mi < 4; ++mi) af[mi]  = *(const short8*)&SA[(arow + mi*16)*32 + slot];
#pragma unroll
    for (int nc = 0; nc < 4; ++nc) bfv[nc] = *(const short8*)&SB[(brow + nc*16)*32 + slot];
    if (t < 30){ STGA(t+2, nstg); STGB(t+2, nstg); }
    __builtin_amdgcn_s_setprio(1);
#pragma unroll
    for (int mi = 0; mi < 4; ++mi)
#pragma unroll
      for (int nc = 0; nc < 4; ++nc)
        acc[mi][nc] = MFMA16(af[mi], bfv[nc], acc[mi][nc]);
    __builtin_amdgcn_s_setprio(0);
    if (t < 30)       asm volatile("s_waitcnt vmcnt(4)" ::: "memory");
    else if (t == 30) asm volatile("s_waitcnt vmcnt(0)" ::: "memory");
    __builtin_amdgcn_s_barrier();
    buf = (buf >= 2) ? 0 : buf + 1;
  }
#undef STGA
#undef STGB

  const int colBase = n0 + (wn << 6) + lr;
#pragma unroll
  for (int mi = 0; mi < 4; ++mi){
    const int row0 = m0 + (wm << 6) + mi*16 + lg*4;
#pragma unroll
    for (int nc = 0; nc < 4; ++nc){
      const int col = colBase + nc*16;
      const float bvv = bias[col];
#pragma unroll
      for (int i = 0; i < 4; ++i)
        Cout[(long)(row0 + i) * 1024 + col] = acc[mi][nc][i] + bvv;
    }
  }
}

// ---------------- flash attention (causal), 8-wave block, KBLK=64 ----------------
__global__ __launch_bounds__(512, 4) void attn(
    const ushort_t* __restrict__ Qb, const ushort_t* __restrict__ Kb,
    const ushort_t* __restrict__ Vt, ushort_t* __restrict__ yb){
  __shared__ __align__(16) ushort_t Ks[2][4096];   // [64 key][64 d]
  __shared__ __align__(16) ushort_t Vs[2][4096];   // [64 d][64 k]
  const int tid = threadIdx.x;
  const int w = tid >> 6, l = tid & 63;
  const int lq = l & 31;
  const int hi = l >> 5;
  const int xcd = blockIdx.x & 7;
  const int idx = blockIdx.x >> 3;          // 0..63
  const int hi5 = idx >> 5;                 // 0/1
  const int bh  = (xcd << 3) + ((idx >> 3) & 3) + hi5 * 4;
  const int qj  = hi5 ? (idx & 7) : 7 - (idx & 7);
  const int qc = (qj << 3) + w;
  const int q0 = qc << 5;
  const int wkt = qc >> 1;
  const int p   = qc & 1;
  const int ktmax = (qj << 2) + 3;
  const ushort_t* Qh = Qb + (long)bh * 131072;
  const ushort_t* Kh = Kb + (long)bh * 131072;
  const ushort_t* Vth = Vt + (long)bh * 131072;
  const int h8 = hi * 8;

  const ushort_t* qp = &Qh[(long)(q0 + lq) * 64 + h8];
  short8 qf0 = *(const short8*)(qp);
  short8 qf1 = *(const short8*)(qp + 16);
  short8 qf2 = *(const short8*)(qp + 32);
  short8 qf3 = *(const short8*)(qp + 48);

  const int stg_is_v = (w >= 4);
  const int wg = stg_is_v ? (w - 4) : w;            // 0..3
  const int row0 = (wg << 3) + (l >> 3);            // 0..31
  const int c8 = (l & 7);
  const int cc = c8 ^ (row0 & 7);
  long src0, src1;
  if (!stg_is_v){
    src0 = ((long)row0 << 6) + (cc << 3);
    src1 = ((long)(row0 + 32) << 6) + (cc << 3);
  } else {
    src0 = ((long)row0 << 11) + (cc << 3);
    src1 = ((long)(row0 + 32) << 11) + (cc << 3);
  }
  const int dst0 = (wg << 9) + (l << 3);
  const int dst1 = 2048 + dst0;

  f32x16 o0 = {}, o1 = {};
  float lsum = 0.f;
  const float cl2 = 0.1803368801111204f;   // log2(e)/8

  if (!stg_is_v){ GL_LDS16(Kh + src0,  &Ks[0][dst0]); GL_LDS16(Kh + src1,  &Ks[0][dst1]); }
  else          { GL_LDS16(Vth + src0, &Vs[0][dst0]); GL_LDS16(Vth + src1, &Vs[0][dst1]); }

  int cur = 0;
  for (int kt = 0; kt <= ktmax; ++kt){
    if (kt < ktmax){
      const long k0n = (long)(kt + 1) << 6;
      if (!stg_is_v){
        GL_LDS16(Kh + (k0n << 6) + src0, &Ks[cur ^ 1][dst0]);
        GL_LDS16(Kh + (k0n << 6) + src1, &Ks[cur ^ 1][dst1]);
      } else {
        GL_LDS16(Vth + k0n + src0, &Vs[cur ^ 1][dst0]);
        GL_LDS16(Vth + k0n + src1, &Vs[cur ^ 1][dst1]);
      }
      asm volatile("s_waitcnt vmcnt(2)" ::: "memory");
    } else {
      asm volatile("s_waitcnt vmcnt(0)" ::: "memory");
    }
    __builtin_amdgcn_s_barrier();
    if (kt <= wkt){
      const bool diag = (kt == wkt);
      const int swl = lq & 7;
#pragma unroll
      for (int ksub = 0; ksub < 2; ++ksub){
        if (diag && ksub > p) continue;
        const ushort_t* kr = &Ks[cur][(ksub * 32 + lq) << 6];
        short8 kf0 = *(const short8*)&kr[((    hi) ^ swl) << 3];
        short8 kf1 = *(const short8*)&kr[((2 + hi) ^ swl) << 3];
        short8 kf2 = *(const short8*)&kr[((4 + hi) ^ swl) << 3];
        short8 kf3 = *(const short8*)&kr[((6 + hi) ^ swl) << 3];
        f32x16 s = {};
        s = MFMA32(kf0, qf0, s);
        s = MFMA32(kf1, qf1, s);
        s = MFMA32(kf2, qf2, s);
        s = MFMA32(kf3, qf3, s);
        if (diag && ksub == p){
#pragma unroll
          for (int r = 0; r < 16; ++r){
            const int rk = (r & 3) + 8 * (r >> 2) + 4 * hi;
            if (rk > lq) s[r] = -1e30f;
          }
        }
#pragma unroll
        for (int r = 0; r < 16; ++r) s[r] = __builtin_amdgcn_exp2f(__builtin_fmaf(s[r], cl2, -2.0f));
        {
          float t0 = (s[0] + s[1]) + (s[2] + s[3]);
          float t1 = (s[4] + s[5]) + (s[6] + s[7]);
          float t2 = (s[8] + s[9]) + (s[10] + s[11]);
          float t3 = (s[12] + s[13]) + (s[14] + s[15]);
          lsum += (t0 + t1) + (t2 + t3);
        }
        uint32 a0 = cvtpk_bf16(s[0], s[1]),  b0 = cvtpk_bf16(s[4], s[5]);
        uint32 a1 = cvtpk_bf16(s[2], s[3]),  b1 = cvtpk_bf16(s[6], s[7]);
        uint32 a2 = cvtpk_bf16(s[8], s[9]),  b2 = cvtpk_bf16(s[12], s[13]);
        uint32 a3 = cvtpk_bf16(s[10], s[11]),b3 = cvtpk_bf16(s[14], s[15]);
        plswap(a0, b0);
        plswap(a1, b1);
        plswap(a2, b2);
        plswap(a3, b3);
        u32x4 pc0 = {a0, a1, b0, b1};
        u32x4 pc1 = {a2, a3, b2, b3};
        short8 pb0 = __builtin_bit_cast(short8, pc0);
        short8 pb1 = __builtin_bit_cast(short8, pc1);
        const ushort_t* vrlo = &Vs[cur][lq << 6];
        const ushort_t* vrhi = &Vs[cur][(lq + 32) << 6];
        const int cbase = ksub << 2;
        short8 vf00 = *(const short8*)&vrlo[((cbase +     hi) ^ swl) << 3];
        short8 vf01 = *(const short8*)&vrlo[((cbase + 2 + hi) ^ swl) << 3];
        short8 vf10 = *(const short8*)&vrhi[((cbase +     hi) ^ swl) << 3];
        short8 vf11 = *(const short8*)&vrhi[((cbase + 2 + hi) ^ swl) << 3];
        o0 = MFMA32(vf00, pb0, o0);
        o0 = MFMA32(vf01, pb1, o0);
        o1 = MFMA32(vf10, pb0, o1);
        o1 = MFMA32(vf11, pb1, o1);
      }
    }
    __builtin_amdgcn_s_barrier();
    cur ^= 1;
  }
  lsum += __shfl_xor(lsum, 32);
  const float inv = 1.0f / lsum;
  const int b = bh >> 4, h = bh & 15;
  const int tok = q0 + lq;
  ushort_t* yrow = yb + (long)(b * 2048 + tok) * 1024 + h * 64;
#pragma unroll
  for (int g = 0; g < 4; ++g){
    short4v p0, p1;
#pragma unroll
    for (int j = 0; j < 4; ++j){
      p0[j] = (short)f2bf(o0[4*g + j] * inv);
      p1[j] = (short)f2bf(o1[4*g + j] * inv);
    }
    *(short4v*)&yrow[8*g + 4*hi]      = p0;
    *(short4v*)&yrow[32 + 8*g + 4*hi] = p1;
  }
}

// ---------------- launch ----------------
extern "C" void kernel_launch(void* const* d_in, const int* in_sizes, int n_in,
                              void* d_out, int out_size, void* d_ws, size_t ws_size,
                              hipStream_t stream){
  const float* x  = (const float*)d_in[0];
  const float* Wq = (const float*)d_in[1];
  const float* bq = (const float*)d_in[2];
  const float* Wk = (const float*)d_in[3];
  const float* bk = (const float*)d_in[4];
  const float* Wv = (const float*)d_in[5];
  const float* bv = (const float*)d_in[6];
  const float* Wo = (const float*)d_in[7];
  const float* bo = (const float*)d_in[8];
  char* ws = (char*)d_ws;
  ushort_t* xb   = (ushort_t*)(ws);                      // 16 MB; reused as yb after attn
  ushort_t* wqkv = (ushort_t*)(ws + 16777216);           // 6 MB (Q,K,V packed)
  ushort_t* wob  = (ushort_t*)(ws + 23068672);           // 2 MB
  float2*   tab  = (float2*)  (ws + 25165824);           // 512 KB
  ushort_t* Qb   = (ushort_t*)(ws + 25690112);           // 16 MB
  ushort_t* Kb   = (ushort_t*)(ws + 42467328);           // 16 MB
  ushort_t* Vt   = (ushort_t*)(ws + 59244544);           // 16 MB
  ushort_t* yb   = xb;

  convert_all<<<6400, 256, 0, stream>>>(x, Wq, Wk, Wv, Wo, xb, wqkv, wob, tab);
  gemm_qkv<<<1536, 256, 0, stream>>>(xb, wqkv, bq, bk, bv, tab, Qb, Kb, Vt);
  attn<<<512, 512, 0, stream>>>(Qb, Kb, Vt, yb);
  gemm_out<<<512, 256, 0, stream>>>(yb, wob, bo, (float*)d_out);
}

// Round 17
// 149.882 us; speedup vs baseline: 1.0340x; 1.0340x over previous
//
#include <hip/hip_runtime.h>
#include <hip/hip_bf16.h>
#include <cstdint>

typedef __attribute__((ext_vector_type(8))) short short8;
typedef __attribute__((ext_vector_type(4))) short short4v;
typedef __attribute__((ext_vector_type(4))) float f32x4;
typedef __attribute__((ext_vector_type(16))) float f32x16;
typedef __attribute__((ext_vector_type(4))) unsigned int u32x4;
typedef unsigned short ushort_t;
typedef unsigned int uint32;

#define DEVI static __device__ __forceinline__

DEVI ushort_t f2bf(float f){
  uint32 u = __builtin_bit_cast(uint32, f);
  u += 0x7FFFu + ((u >> 16) & 1u);
  return (ushort_t)(u >> 16);
}
DEVI uint32 cvtpk_bf16(float lo, float hi){
  uint32 r;
  asm("v_cvt_pk_bf16_f32 %0, %1, %2" : "=v"(r) : "v"(lo), "v"(hi));
  return r;
}
DEVI void plswap(uint32& a, uint32& b){
  asm("v_permlane32_swap_b32 %0, %1" : "+v"(a), "+v"(b));
}

typedef __attribute__((address_space(1))) const uint32 g_u32;
typedef __attribute__((address_space(3))) uint32 l_u32;
#define GL_LDS16(gp, lp) __builtin_amdgcn_global_load_lds((g_u32*)(gp), (l_u32*)(lp), 16, 0, 0)

#define MFMA16(a, b, c) __builtin_amdgcn_mfma_f32_16x16x32_bf16(a, b, c, 0, 0, 0)
#define MFMA32(a, b, c) __builtin_amdgcn_mfma_f32_32x32x16_bf16(a, b, c, 0, 0, 0)

// ---------------- fp32 -> bf16 conversion + rope table ----------------
__global__ __launch_bounds__(256) void convert_all(
    const float* __restrict__ x, const float* __restrict__ wq, const float* __restrict__ wk,
    const float* __restrict__ wv, const float* __restrict__ wo,
    ushort_t* __restrict__ xb, ushort_t* __restrict__ wqkv, ushort_t* __restrict__ wob,
    float2* __restrict__ tab){
  int bid = blockIdx.x;
  if (bid >= 6144){
    const int idx = (bid - 6144) * 256 + threadIdx.x;    // 65536
    const int tok = idx >> 5, j = idx & 31;
    const float theta = exp2f(-(float)j * 0.4152410118609203f);   // log2(10000)/32
    const float ang = (float)(tok + 1) * theta;
    float s, c;
    sincosf(ang, &s, &c);
    tab[idx] = make_float2(c, s);
    return;
  }
  const float* src; ushort_t* dst; long base;
  if (bid < 4096){ src = x; dst = xb; base = (long)bid * 2048; }
  else {
    int r = bid - 4096; int sel = r >> 9; int o = r & 511;
    src = sel==0?wq: sel==1?wk: sel==2?wv: wo;
    dst = (sel<3) ? (wqkv + (long)sel * 1048576) : wob;
    base = (long)o * 2048;
  }
  long i = base + (long)threadIdx.x * 8;
  const float* p = src + i;
  float4 a = *(const float4*)p;
  float4 b = *(const float4*)(p + 4);
  short8 v;
  v[0]=(short)f2bf(a.x); v[1]=(short)f2bf(a.y); v[2]=(short)f2bf(a.z); v[3]=(short)f2bf(a.w);
  v[4]=(short)f2bf(b.x); v[5]=(short)f2bf(b.y); v[6]=(short)f2bf(b.z); v[7]=(short)f2bf(b.w);
  *(short8*)(dst + i) = v;
}

// ---------------- QKV GEMM, 256x128 tile, BK=32, tri-buffered, 1 barrier/tile ----------------
// (r13 best: 72 KB LDS -> 2 blocks/CU, 63.0 us, MfmaUtil 35%)
__global__ __launch_bounds__(512, 2) void gemm_qkv(
    const ushort_t* __restrict__ A, const ushort_t* __restrict__ Bw,
    const float* __restrict__ bq, const float* __restrict__ bk, const float* __restrict__ bv,
    const float2* __restrict__ tab,
    ushort_t* __restrict__ Qb, ushort_t* __restrict__ Kb, ushort_t* __restrict__ Vt){
  __shared__ __align__(16) ushort_t S[36864];   // 72 KB: 3 bufs x (A 16KB | B 8KB)
  const int tid = threadIdx.x;
  const int w = tid >> 6, l = tid & 63, lr = l & 15, lg = l >> 4;
  const int wm = w >> 1, wn = w & 1;            // 4M x 2N
  const int xcd = blockIdx.x & 7;
  const int l9  = blockIdx.x >> 3;              // 0..95
  const int bg  = l9 >> 5;                      // 0..2
  const int rem = l9 & 31;
  const int bm  = ((xcd & 3) << 3) + (rem >> 2);
  const int bn  = ((xcd >> 2) * 12) + (bg << 2) + (rem & 3);
  const int m0 = bm << 8, n0 = bn << 7;
  const int rbase = tid >> 2;
  const int swzk = (tid & 3) ^ ((tid >> 3) & 3);
  const ushort_t* aS = A  + (long)(m0 + rbase) * 1024 + swzk * 8;
  const ushort_t* bS = Bw + (long)(n0 + rbase) * 1024 + swzk * 8;
  const int slot = (lg ^ ((lr >> 1) & 3)) << 3;
  const int arow = wm * 64 + lr;
  const int brow = wn * 64 + lr;
  f32x4 acc[4][4] = {};

#define STGA(t, bf_) do{ \
    const ushort_t* _s = aS + (long)(t)*32; \
    ushort_t* _d = &S[(bf_)*12288 + tid*8]; \
    GL_LDS16(_s,          _d); \
    GL_LDS16(_s + 131072, _d + 4096); }while(0)
#define STGB(t, bf_) do{ \
    GL_LDS16(bS + (long)(t)*32, &S[(bf_)*12288 + 8192 + tid*8]); }while(0)

  STGA(0,0); STGB(0,0);
  STGA(1,1); STGB(1,1);
  asm volatile("s_waitcnt vmcnt(3)" ::: "memory");
  __builtin_amdgcn_s_barrier();

  int buf = 0;
  for (int t = 0; t < 32; ++t){
    const int nstg = (buf >= 1) ? buf - 1 : 2;     // (t+2)%3
    const ushort_t* SA = &S[buf * 12288];
    const ushort_t* SB = &S[buf * 12288 + 8192];
    short8 af[4], bfv[4];
#pragma unroll
    for (int mi = 0; mi < 4; ++mi) af[mi]  = *(const short8*)&SA[(arow + mi*16)*32 + slot];
#pragma unroll
    for (int nc = 0; nc < 4; ++nc) bfv[nc] = *(const short8*)&SB[(brow + nc*16)*32 + slot];
    if (t < 30){ STGA(t+2, nstg); STGB(t+2, nstg); }
    __builtin_amdgcn_s_setprio(1);
#pragma unroll
    for (int mi = 0; mi < 4; ++mi)
#pragma unroll
      for (int nc = 0; nc < 4; ++nc)
        acc[mi][nc] = MFMA16(af[mi], bfv[nc], acc[mi][nc]);
    __builtin_amdgcn_s_setprio(0);
    if (t < 30)       asm volatile("s_waitcnt vmcnt(3)" ::: "memory");
    else if (t == 30) asm volatile("s_waitcnt vmcnt(0)" ::: "memory");
    __builtin_amdgcn_s_barrier();
    buf = (buf >= 2) ? 0 : buf + 1;
  }
#undef STGA
#undef STGB

  const int colX = n0 + (wn << 6);
  const int sel = colX >> 10;                // 0=Q 1=K 2=V
  const int h = (colX >> 6) & 15;
  const int cB = (colX & 1023) + lr;
  if (sel < 2){
    ushort_t* dst = sel ? Kb : Qb;
    const float* bp = sel ? bk : bq;
    const float bvs[4] = {bp[cB], bp[cB+16], bp[cB+32], bp[cB+48]};
#pragma unroll
    for (int mi = 0; mi < 4; ++mi){
      const int row0 = m0 + (wm << 6) + mi*16 + lg*4;
#pragma unroll
      for (int i = 0; i < 4; ++i){
        const int r = row0 + i;
        const int b = r >> 11, tok = r & 2047;
#pragma unroll
        for (int nc = 0; nc < 2; ++nc){
          const int j = nc*16 + lr;
          const float2 cs = tab[tok*32 + j];
          const float v0 = acc[mi][nc][i]   + bvs[nc];
          const float v1 = acc[mi][nc+2][i] + bvs[nc+2];
          const long base = (((long)((b<<4) + h) * 2048 + tok) << 6) + j;
          dst[base]      = f2bf(v0 * cs.x - v1 * cs.y);
          dst[base + 32] = f2bf(v1 * cs.x + v0 * cs.y);
        }
      }
    }
  } else {
    // V: LDS transpose -> coalesced Vt writes (wave-private 4608-ushort region)
    const float bvs[4] = {bv[cB], bv[cB+16], bv[cB+32], bv[cB+48]};
    ushort_t* T = &S[w * 4608];
#pragma unroll
    for (int nc = 0; nc < 4; ++nc){
      const int d = nc*16 + lr;
      const int dx = d & 7;
#pragma unroll
      for (int mi = 0; mi < 4; ++mi){
        const int col = mi*16 + lg*4;
        const int scol = (((col >> 3) ^ dx) << 3) + (col & 7);
        const uint32 p0 = cvtpk_bf16(acc[mi][nc][0] + bvs[nc], acc[mi][nc][1] + bvs[nc]);
        const uint32 p1 = cvtpk_bf16(acc[mi][nc][2] + bvs[nc], acc[mi][nc][3] + bvs[nc]);
        uint32* dp = (uint32*)&T[d*72 + scol];
        dp[0] = p0; dp[1] = p1;
      }
    }
    const int rowbase = m0 + (wm << 6);
    const int b = rowbase >> 11;
    const int tok0 = rowbase & 2047;
    ushort_t* vbase = Vt + (((long)((b << 4) + h)) << 17);   // *64*2048
    const int dl = l >> 3, c8 = l & 7;
#pragma unroll
    for (int it = 0; it < 8; ++it){
      const int d = dl + it*8;
      short8 v = *(const short8*)&T[d*72 + ((c8 ^ (d & 7)) << 3)];
      *(short8*)&vbase[((long)d << 11) + tok0 + (c8 << 3)] = v;
    }
  }
}

// ---------------- output GEMM, 128x128 tile, BK=32, tri-buffered ----------------
__global__ __launch_bounds__(256, 3) void gemm_out(
    const ushort_t* __restrict__ A, const ushort_t* __restrict__ Bw,
    const float* __restrict__ bias, float* __restrict__ Cout){
  __shared__ __align__(16) ushort_t S[24576];   // 48 KB
  const int tid = threadIdx.x;
  const int w = tid >> 6, l = tid & 63, lr = l & 15, lg = l >> 4;
  const int wm = w >> 1, wn = w & 1;
  const int xcd = blockIdx.x & 7;
  const int l6  = blockIdx.x >> 3;              // 0..63
  const int bm  = (xcd << 3) + (l6 >> 3);       // 0..63
  const int bn  = l6 & 7;
  const int m0 = bm << 7, n0 = bn << 7;
  const int rbase = tid >> 2;
  const int swzk = (tid & 3) ^ ((tid >> 3) & 3);
  const ushort_t* aS = A  + (long)(m0 + rbase) * 1024 + swzk * 8;
  const ushort_t* bS = Bw + (long)(n0 + rbase) * 1024 + swzk * 8;
  const int slot = (lg ^ ((lr >> 1) & 3)) << 3;
  const int arow = wm * 64 + lr;
  const int brow = wn * 64 + lr;
  f32x4 acc[4][4] = {};

#define STGA(t, bf_) do{ \
    const ushort_t* _s = aS + (long)(t)*32; \
    ushort_t* _d = &S[(bf_)*8192 + tid*8]; \
    GL_LDS16(_s,         _d); \
    GL_LDS16(_s + 65536, _d + 2048); }while(0)
#define STGB(t, bf_) do{ \
    const ushort_t* _s = bS + (long)(t)*32; \
    ushort_t* _d = &S[(bf_)*8192 + 4096 + tid*8]; \
    GL_LDS16(_s,         _d); \
    GL_LDS16(_s + 65536, _d + 2048); }while(0)

  STGA(0,0); STGB(0,0);
  STGA(1,1); STGB(1,1);
  asm volatile("s_waitcnt vmcnt(4)" ::: "memory");
  __builtin_amdgcn_s_barrier();

  int buf = 0;
  for (int t = 0; t < 32; ++t){
    const int nstg = (buf >= 1) ? buf - 1 : 2;
    const ushort_t* SA = &S[buf * 8192];
    const ushort_t* SB = &S[buf * 8192 + 4096];
    short8 af[4], bfv[4];
#pragma unroll
    for (int mi = 0; mi < 4; ++mi) af[mi]  = *(const short8*)&SA[(arow + mi*16)*32 + slot];
#pragma unroll
    for (int nc = 0; nc < 4; ++nc) bfv[nc] = *(const short8*)&SB[(brow + nc*16)*32 + slot];
    if (t < 30){ STGA(t+2, nstg); STGB(t+2, nstg); }
    __builtin_amdgcn_s_setprio(1);
#pragma unroll
    for (int mi = 0; mi < 4; ++mi)
#pragma unroll
      for (int nc = 0; nc < 4; ++nc)
        acc[mi][nc] = MFMA16(af[mi], bfv[nc], acc[mi][nc]);
    __builtin_amdgcn_s_setprio(0);
    if (t < 30)       asm volatile("s_waitcnt vmcnt(4)" ::: "memory");
    else if (t == 30) asm volatile("s_waitcnt vmcnt(0)" ::: "memory");
    __builtin_amdgcn_s_barrier();
    buf = (buf >= 2) ? 0 : buf + 1;
  }
#undef STGA
#undef STGB

  const int colBase = n0 + (wn << 6) + lr;
#pragma unroll
  for (int mi = 0; mi < 4; ++mi){
    const int row0 = m0 + (wm << 6) + mi*16 + lg*4;
#pragma unroll
    for (int nc = 0; nc < 4; ++nc){
      const int col = colBase + nc*16;
      const float bvv = bias[col];
#pragma unroll
      for (int i = 0; i < 4; ++i)
        Cout[(long)(row0 + i) * 1024 + col] = acc[mi][nc][i] + bvv;
    }
  }
}

// ---------------- flash attention (causal), 8-wave block, KBLK=64, setprio ----------------
__global__ __launch_bounds__(512, 4) void attn(
    const ushort_t* __restrict__ Qb, const ushort_t* __restrict__ Kb,
    const ushort_t* __restrict__ Vt, ushort_t* __restrict__ yb){
  __shared__ __align__(16) ushort_t Ks[2][4096];   // [64 key][64 d]
  __shared__ __align__(16) ushort_t Vs[2][4096];   // [64 d][64 k]
  const int tid = threadIdx.x;
  const int w = tid >> 6, l = tid & 63;
  const int lq = l & 31;
  const int hi = l >> 5;
  const int xcd = blockIdx.x & 7;
  const int idx = blockIdx.x >> 3;          // 0..63
  const int hi5 = idx >> 5;                 // 0/1
  const int bh  = (xcd << 3) + ((idx >> 3) & 3) + hi5 * 4;
  const int qj  = hi5 ? (idx & 7) : 7 - (idx & 7);
  const int qc = (qj << 3) + w;
  const int q0 = qc << 5;
  const int wkt = qc >> 1;
  const int p   = qc & 1;
  const int ktmax = (qj << 2) + 3;
  const ushort_t* Qh = Qb + (long)bh * 131072;
  const ushort_t* Kh = Kb + (long)bh * 131072;
  const ushort_t* Vth = Vt + (long)bh * 131072;
  const int h8 = hi * 8;

  const ushort_t* qp = &Qh[(long)(q0 + lq) * 64 + h8];
  short8 qf0 = *(const short8*)(qp);
  short8 qf1 = *(const short8*)(qp + 16);
  short8 qf2 = *(const short8*)(qp + 32);
  short8 qf3 = *(const short8*)(qp + 48);

  const int stg_is_v = (w >= 4);
  const int wg = stg_is_v ? (w - 4) : w;            // 0..3
  const int row0 = (wg << 3) + (l >> 3);            // 0..31
  const int c8 = (l & 7);
  const int cc = c8 ^ (row0 & 7);
  long src0, src1;
  if (!stg_is_v){
    src0 = ((long)row0 << 6) + (cc << 3);
    src1 = ((long)(row0 + 32) << 6) + (cc << 3);
  } else {
    src0 = ((long)row0 << 11) + (cc << 3);
    src1 = ((long)(row0 + 32) << 11) + (cc << 3);
  }
  const int dst0 = (wg << 9) + (l << 3);
  const int dst1 = 2048 + dst0;

  f32x16 o0 = {}, o1 = {};
  float lsum = 0.f;
  const float cl2 = 0.1803368801111204f;   // log2(e)/8

  if (!stg_is_v){ GL_LDS16(Kh + src0,  &Ks[0][dst0]); GL_LDS16(Kh + src1,  &Ks[0][dst1]); }
  else          { GL_LDS16(Vth + src0, &Vs[0][dst0]); GL_LDS16(Vth + src1, &Vs[0][dst1]); }

  int cur = 0;
  for (int kt = 0; kt <= ktmax; ++kt){
    if (kt < ktmax){
      const long k0n = (long)(kt + 1) << 6;
      if (!stg_is_v){
        GL_LDS16(Kh + (k0n << 6) + src0, &Ks[cur ^ 1][dst0]);
        GL_LDS16(Kh + (k0n << 6) + src1, &Ks[cur ^ 1][dst1]);
      } else {
        GL_LDS16(Vth + k0n + src0, &Vs[cur ^ 1][dst0]);
        GL_LDS16(Vth + k0n + src1, &Vs[cur ^ 1][dst1]);
      }
      asm volatile("s_waitcnt vmcnt(2)" ::: "memory");
    } else {
      asm volatile("s_waitcnt vmcnt(0)" ::: "memory");
    }
    __builtin_amdgcn_s_barrier();
    if (kt <= wkt){
      const bool diag = (kt == wkt);
      const int swl = lq & 7;
      __builtin_amdgcn_s_setprio(1);
#pragma unroll
      for (int ksub = 0; ksub < 2; ++ksub){
        if (diag && ksub > p) continue;
        const ushort_t* kr = &Ks[cur][(ksub * 32 + lq) << 6];
        short8 kf0 = *(const short8*)&kr[((    hi) ^ swl) << 3];
        short8 kf1 = *(const short8*)&kr[((2 + hi) ^ swl) << 3];
        short8 kf2 = *(const short8*)&kr[((4 + hi) ^ swl) << 3];
        short8 kf3 = *(const short8*)&kr[((6 + hi) ^ swl) << 3];
        f32x16 s = {};
        s = MFMA32(kf0, qf0, s);
        s = MFMA32(kf1, qf1, s);
        s = MFMA32(kf2, qf2, s);
        s = MFMA32(kf3, qf3, s);
        if (diag && ksub == p){
#pragma unroll
          for (int r = 0; r < 16; ++r){
            const int rk = (r & 3) + 8 * (r >> 2) + 4 * hi;
            if (rk > lq) s[r] = -1e30f;
          }
        }
#pragma unroll
        for (int r = 0; r < 16; ++r) s[r] = __builtin_amdgcn_exp2f(__builtin_fmaf(s[r], cl2, -2.0f));
        {
          float t0 = (s[0] + s[1]) + (s[2] + s[3]);
          float t1 = (s[4] + s[5]) + (s[6] + s[7]);
          float t2 = (s[8] + s[9]) + (s[10] + s[11]);
          float t3 = (s[12] + s[13]) + (s[14] + s[15]);
          lsum += (t0 + t1) + (t2 + t3);
        }
        uint32 a0 = cvtpk_bf16(s[0], s[1]),  b0 = cvtpk_bf16(s[4], s[5]);
        uint32 a1 = cvtpk_bf16(s[2], s[3]),  b1 = cvtpk_bf16(s[6], s[7]);
        uint32 a2 = cvtpk_bf16(s[8], s[9]),  b2 = cvtpk_bf16(s[12], s[13]);
        uint32 a3 = cvtpk_bf16(s[10], s[11]),b3 = cvtpk_bf16(s[14], s[15]);
        plswap(a0, b0);
        plswap(a1, b1);
        plswap(a2, b2);
        plswap(a3, b3);
        u32x4 pc0 = {a0, a1, b0, b1};
        u32x4 pc1 = {a2, a3, b2, b3};
        short8 pb0 = __builtin_bit_cast(short8, pc0);
        short8 pb1 = __builtin_bit_cast(short8, pc1);
        const ushort_t* vrlo = &Vs[cur][lq << 6];
        const ushort_t* vrhi = &Vs[cur][(lq + 32) << 6];
        const int cbase = ksub << 2;
        short8 vf00 = *(const short8*)&vrlo[((cbase +     hi) ^ swl) << 3];
        short8 vf01 = *(const short8*)&vrlo[((cbase + 2 + hi) ^ swl) << 3];
        short8 vf10 = *(const short8*)&vrhi[((cbase +     hi) ^ swl) << 3];
        short8 vf11 = *(const short8*)&vrhi[((cbase + 2 + hi) ^ swl) << 3];
        o0 = MFMA32(vf00, pb0, o0);
        o0 = MFMA32(vf01, pb1, o0);
        o1 = MFMA32(vf10, pb0, o1);
        o1 = MFMA32(vf11, pb1, o1);
      }
      __builtin_amdgcn_s_setprio(0);
    }
    __builtin_amdgcn_s_barrier();
    cur ^= 1;
  }
  lsum += __shfl_xor(lsum, 32);
  const float inv = 1.0f / lsum;
  const int b = bh >> 4, h = bh & 15;
  const int tok = q0 + lq;
  ushort_t* yrow = yb + (long)(b * 2048 + tok) * 1024 + h * 64;
#pragma unroll
  for (int g = 0; g < 4; ++g){
    short4v p0, p1;
#pragma unroll
    for (int j = 0; j < 4; ++j){
      p0[j] = (short)f2bf(o0[4*g + j] * inv);
      p1[j] = (short)f2bf(o1[4*g + j] * inv);
    }
    *(short4v*)&yrow[8*g + 4*hi]      = p0;
    *(short4v*)&yrow[32 + 8*g + 4*hi] = p1;
  }
}

// ---------------- launch ----------------
extern "C" void kernel_launch(void* const* d_in, const int* in_sizes, int n_in,
                              void* d_out, int out_size, void* d_ws, size_t ws_size,
                              hipStream_t stream){
  const float* x  = (const float*)d_in[0];
  const float* Wq = (const float*)d_in[1];
  const float* bq = (const float*)d_in[2];
  const float* Wk = (const float*)d_in[3];
  const float* bk = (const float*)d_in[4];
  const float* Wv = (const float*)d_in[5];
  const float* bv = (const float*)d_in[6];
  const float* Wo = (const float*)d_in[7];
  const float* bo = (const float*)d_in[8];
  char* ws = (char*)d_ws;
  ushort_t* xb   = (ushort_t*)(ws);                      // 16 MB; reused as yb after attn
  ushort_t* wqkv = (ushort_t*)(ws + 16777216);           // 6 MB (Q,K,V packed)
  ushort_t* wob  = (ushort_t*)(ws + 23068672);           // 2 MB
  float2*   tab  = (float2*)  (ws + 25165824);           // 512 KB
  ushort_t* Qb   = (ushort_t*)(ws + 25690112);           // 16 MB
  ushort_t* Kb   = (ushort_t*)(ws + 42467328);           // 16 MB
  ushort_t* Vt   = (ushort_t*)(ws + 59244544);           // 16 MB
  ushort_t* yb   = xb;

  convert_all<<<6400, 256, 0, stream>>>(x, Wq, Wk, Wv, Wo, xb, wqkv, wob, tab);
  gemm_qkv<<<768, 512, 0, stream>>>(xb, wqkv, bq, bk, bv, tab, Qb, Kb, Vt);
  attn<<<512, 512, 0, stream>>>(Qb, Kb, Vt, yb);
  gemm_out<<<512, 256, 0, stream>>>(yb, wob, bo, (float*)d_out);
}